// Round 3
// baseline (336.536 us; speedup 1.0000x reference)
//
#include <hip/hip_runtime.h>

// MoonLoss: mean((out' - tgt')^2) over [B=8388608, F=5] f32.
// Columns 1..4 circular: out' = mod(out,1); tgt' = tgt + wrap-shift.
// Column 0 linear: out' = out, tgt' = tgt.
// Memory-bound: 335.5 MB read -> ~53us floor at 6.3 TB/s.

constexpr unsigned int BDIM = 8388608u;
constexpr unsigned int FDIM = 5u;
constexpr unsigned int NTOT = BDIM * FDIM;        // 41,943,040
constexpr unsigned int NCHUNK = NTOT / 4u;        // 10,485,760 float4 chunks
constexpr int NBLOCKS = 2048;
constexpr int NTHREADS = 256;

__global__ __launch_bounds__(NTHREADS) void moonloss_partial(
    const float* __restrict__ outp,
    const float* __restrict__ tgtp,
    float* __restrict__ partial) {
  unsigned int tid = blockIdx.x * blockDim.x + threadIdx.x;
  unsigned int stride = gridDim.x * blockDim.x;

  float acc = 0.0f;
  for (unsigned int c = tid; c < NCHUNK; c += stride) {
    float4 o4 = reinterpret_cast<const float4*>(outp)[c];
    float4 t4 = reinterpret_cast<const float4*>(tgtp)[c];
    float o[4] = {o4.x, o4.y, o4.z, o4.w};
    float t[4] = {t4.x, t4.y, t4.z, t4.w};
    unsigned int base = c * 4u;
#pragma unroll
    for (int j = 0; j < 4; ++j) {
      unsigned int col = (base + (unsigned int)j) % FDIM;  // magic-mul, cheap
      float oo = o[j];
      float tt = t[j];
      bool circ = (col != 0u);
      if (circ) oo = oo - floorf(oo);          // jnp.mod(o, 1.0)
      float d = oo - tt;
      float shift = (fabsf(d) > 0.5f) ? ((tt < oo) ? 1.0f : -1.0f) : 0.0f;
      float tw = circ ? (tt + shift) : tt;
      float diff = oo - tw;
      acc = fmaf(diff, diff, acc);
    }
  }

  // wave64 shuffle reduction
#pragma unroll
  for (int off = 32; off > 0; off >>= 1) acc += __shfl_down(acc, off, 64);

  __shared__ float sacc[NTHREADS / 64];
  int wid = threadIdx.x >> 6;
  if ((threadIdx.x & 63) == 0) sacc[wid] = acc;
  __syncthreads();
  if (threadIdx.x == 0) {
    float s = 0.0f;
#pragma unroll
    for (int w = 0; w < NTHREADS / 64; ++w) s += sacc[w];
    partial[blockIdx.x] = s;  // every block writes -> ws poison overwritten
  }
}

__global__ __launch_bounds__(256) void moonloss_final(
    const float* __restrict__ partial, int n, float* __restrict__ out) {
  double acc = 0.0;
  for (int i = threadIdx.x; i < n; i += blockDim.x) acc += (double)partial[i];
  __shared__ double s[256];
  s[threadIdx.x] = acc;
  __syncthreads();
  for (int off = 128; off > 0; off >>= 1) {
    if (threadIdx.x < off) s[threadIdx.x] += s[threadIdx.x + off];
    __syncthreads();
  }
  if (threadIdx.x == 0) out[0] = (float)(s[0] / (double)NTOT);
}

extern "C" void kernel_launch(void* const* d_in, const int* in_sizes, int n_in,
                              void* d_out, int out_size, void* d_ws, size_t ws_size,
                              hipStream_t stream) {
  const float* outputs = (const float*)d_in[0];
  const float* targets = (const float*)d_in[1];
  float* out = (float*)d_out;
  float* partial = (float*)d_ws;  // NBLOCKS floats

  moonloss_partial<<<NBLOCKS, NTHREADS, 0, stream>>>(outputs, targets, partial);
  moonloss_final<<<1, 256, 0, stream>>>(partial, NBLOCKS, out);
}